// Round 1
// baseline (715.641 us; speedup 1.0000x reference)
//
#include <hip/hip_runtime.h>
#include <math.h>

#define T_DIM   2048
#define B_DIM   128
#define E_DIM   512
#define NSPLIT  8
#define TC      (T_DIM / NSPLIT)   // 256 timesteps per workgroup, 64 per wave

__device__ __forceinline__ float wave_reduce_sum(float v) {
    // butterfly: all 64 lanes end with the full sum
    v += __shfl_xor(v, 1,  64);
    v += __shfl_xor(v, 2,  64);
    v += __shfl_xor(v, 4,  64);
    v += __shfl_xor(v, 8,  64);
    v += __shfl_xor(v, 16, 64);
    v += __shfl_xor(v, 32, 64);
    return v;
}

// Kernel A: xp[b,e] = sum_k x[b,k] * W[e,k] + bias[e]
// grid (B, 4); each block handles 128 e's for one b; one wave per dot.
__global__ __launch_bounds__(256) void proj_kernel(
    const float* __restrict__ x, const float* __restrict__ W,
    const float* __restrict__ bias, float* __restrict__ xp,
    float* __restrict__ out)
{
    const int b      = blockIdx.x;
    const int echunk = blockIdx.y;     // 0..3
    const int tid    = threadIdx.x;
    const int lane   = tid & 63;
    const int wave   = tid >> 6;

    const float4* x4 = (const float4*)(x + (size_t)b * E_DIM);
    const float4 xq0 = x4[lane];
    const float4 xq1 = x4[64 + lane];

    const int ebase = echunk * 128;
    for (int e = ebase + wave; e < ebase + 128; e += 4) {
        const float4* w4 = (const float4*)(W + (size_t)e * E_DIM);
        const float4 w0 = w4[lane];
        const float4 w1 = w4[64 + lane];
        float p = w0.x*xq0.x + w0.y*xq0.y + w0.z*xq0.z + w0.w*xq0.w;
        p      += w1.x*xq1.x + w1.y*xq1.y + w1.z*xq1.z + w1.w*xq1.w;
        p = wave_reduce_sum(p);
        if (lane == 0) {
            float v = p + bias[e];
            xp[(size_t)b * E_DIM + e] = v;
            out[(size_t)b * (2 * E_DIM) + e] = v;   // first half of output = xp
        }
    }
}

// Kernel B: flash-decode partials. grid (B, NSPLIT), 256 threads (4 waves).
// Each wave processes 64 contiguous timesteps with online softmax; lane holds
// 8 context-accumulator elements (e = 4*lane..4*lane+3 and 256+4*lane..+3).
__global__ __launch_bounds__(256) void attn_partial_kernel(
    const float* __restrict__ enc, const float* __restrict__ xp,
    float* __restrict__ m_part, float* __restrict__ l_part,
    float* __restrict__ acc_part)
{
    const int b    = blockIdx.x;
    const int s    = blockIdx.y;
    const int tid  = threadIdx.x;
    const int lane = tid & 63;
    const int wave = tid >> 6;

    const float4* xp4 = (const float4*)(xp + (size_t)b * E_DIM);
    const float4 xq0 = xp4[lane];
    const float4 xq1 = xp4[64 + lane];

    float m = -INFINITY;
    float l = 0.0f;
    float4 a0 = make_float4(0.f, 0.f, 0.f, 0.f);
    float4 a1 = make_float4(0.f, 0.f, 0.f, 0.f);

    const int t0 = s * TC + wave * (TC / 4);
    for (int i = 0; i < TC / 4; ++i) {
        const int t = t0 + i;
        const float4* e4 = (const float4*)(enc + ((size_t)t * B_DIM + b) * E_DIM);
        const float4 e0 = e4[lane];
        const float4 e1 = e4[64 + lane];

        float p = e0.x*xq0.x + e0.y*xq0.y + e0.z*xq0.z + e0.w*xq0.w;
        p      += e1.x*xq1.x + e1.y*xq1.y + e1.z*xq1.z + e1.w*xq1.w;
        p = wave_reduce_sum(p);            // score s[b,t], same on all lanes

        const float m_new = fmaxf(m, p);
        const float scale = __expf(m - m_new);   // exp(-inf)=0 on first iter
        const float pt    = __expf(p - m_new);
        l = l * scale + pt;
        a0.x = a0.x * scale + pt * e0.x;
        a0.y = a0.y * scale + pt * e0.y;
        a0.z = a0.z * scale + pt * e0.z;
        a0.w = a0.w * scale + pt * e0.w;
        a1.x = a1.x * scale + pt * e1.x;
        a1.y = a1.y * scale + pt * e1.y;
        a1.z = a1.z * scale + pt * e1.z;
        a1.w = a1.w * scale + pt * e1.w;
        m = m_new;
    }

    // Combine the 4 waves of this workgroup via LDS.
    __shared__ float lds_m[4];
    __shared__ float lds_l[4];
    __shared__ __align__(16) float lds_acc[4][E_DIM];

    if (lane == 0) lds_m[wave] = m;
    __syncthreads();
    const float M = fmaxf(fmaxf(lds_m[0], lds_m[1]), fmaxf(lds_m[2], lds_m[3]));
    const float wscale = __expf(m - M);   // wave-uniform

    float4* lacc = (float4*)&lds_acc[wave][0];
    lacc[lane]      = make_float4(a0.x*wscale, a0.y*wscale, a0.z*wscale, a0.w*wscale);
    lacc[64 + lane] = make_float4(a1.x*wscale, a1.y*wscale, a1.z*wscale, a1.w*wscale);
    if (lane == 0) lds_l[wave] = l * wscale;
    __syncthreads();

    const int pid = b * NSPLIT + s;
    if (tid == 0) {
        m_part[pid] = M;
        l_part[pid] = lds_l[0] + lds_l[1] + lds_l[2] + lds_l[3];
    }
    if (tid < 128) {   // 128 float4 chunks of the 512-float accumulator
        float4 sum = make_float4(0.f, 0.f, 0.f, 0.f);
        for (int w = 0; w < 4; ++w) {
            const float4 v = ((const float4*)&lds_acc[w][0])[tid];
            sum.x += v.x; sum.y += v.y; sum.z += v.z; sum.w += v.w;
        }
        ((float4*)(acc_part + (size_t)pid * E_DIM))[tid] = sum;
    }
}

// Kernel C: merge NSPLIT partials per b, write context to out[:, 512:1024].
__global__ __launch_bounds__(128) void combine_kernel(
    const float* __restrict__ m_part, const float* __restrict__ l_part,
    const float* __restrict__ acc_part, float* __restrict__ out)
{
    const int b   = blockIdx.x;
    const int tid = threadIdx.x;   // 0..127, one float4 chunk each

    float M = -INFINITY;
    for (int s = 0; s < NSPLIT; ++s) M = fmaxf(M, m_part[b * NSPLIT + s]);
    float w[NSPLIT];
    float L = 0.f;
    for (int s = 0; s < NSPLIT; ++s) {
        w[s] = __expf(m_part[b * NSPLIT + s] - M);
        L += w[s] * l_part[b * NSPLIT + s];
    }
    const float inv = 1.0f / L;

    float4 sum = make_float4(0.f, 0.f, 0.f, 0.f);
    for (int s = 0; s < NSPLIT; ++s) {
        const float4 v = ((const float4*)(acc_part + (size_t)(b * NSPLIT + s) * E_DIM))[tid];
        sum.x += w[s] * v.x; sum.y += w[s] * v.y;
        sum.z += w[s] * v.z; sum.w += w[s] * v.w;
    }
    const float4 r = make_float4(sum.x*inv, sum.y*inv, sum.z*inv, sum.w*inv);
    ((float4*)(out + (size_t)b * (2 * E_DIM) + E_DIM))[tid] = r;
}

extern "C" void kernel_launch(void* const* d_in, const int* in_sizes, int n_in,
                              void* d_out, int out_size, void* d_ws, size_t ws_size,
                              hipStream_t stream) {
    (void)in_sizes; (void)n_in; (void)out_size; (void)ws_size;
    const float* x    = (const float*)d_in[0];   // [B, 512]
    const float* enc  = (const float*)d_in[1];   // [T, B, 512]
    const float* W    = (const float*)d_in[2];   // [512, 512]
    const float* bias = (const float*)d_in[3];   // [512]
    float* out = (float*)d_out;                  // [B, 1024]

    // Workspace layout (floats): xp[65536] | m_part[1024] | l_part[1024] | acc_part[524288]
    float* ws       = (float*)d_ws;
    float* xp       = ws;
    float* m_part   = ws + 65536;
    float* l_part   = ws + 66560;
    float* acc_part = ws + 67584;

    proj_kernel<<<dim3(B_DIM, 4), 256, 0, stream>>>(x, W, bias, xp, out);
    attn_partial_kernel<<<dim3(B_DIM, NSPLIT), 256, 0, stream>>>(enc, xp, m_part, l_part, acc_part);
    combine_kernel<<<B_DIM, 128, 0, stream>>>(m_part, l_part, acc_part, out);
}

// Round 2
// 713.918 us; speedup vs baseline: 1.0024x; 1.0024x over previous
//
#include <hip/hip_runtime.h>
#include <math.h>

#define T_DIM   2048
#define B_DIM   128
#define E_DIM   512
#define NSPLIT  16
#define TC      (T_DIM / NSPLIT)    // 128 timesteps per workgroup
#define TW      (TC / 4)            // 32 timesteps per wave
#define ROWS    4                   // t-rows batched per iteration

__device__ __forceinline__ float wave_reduce_sum(float v) {
    v += __shfl_xor(v, 1,  64);
    v += __shfl_xor(v, 2,  64);
    v += __shfl_xor(v, 4,  64);
    v += __shfl_xor(v, 8,  64);
    v += __shfl_xor(v, 16, 64);
    v += __shfl_xor(v, 32, 64);
    return v;
}

__device__ __forceinline__ float4 wave_reduce_sum4(float4 v) {
    #pragma unroll
    for (int mask = 1; mask < 64; mask <<= 1) {
        // 4 independent shfls per stage — pipeline instead of serialize
        v.x += __shfl_xor(v.x, mask, 64);
        v.y += __shfl_xor(v.y, mask, 64);
        v.z += __shfl_xor(v.z, mask, 64);
        v.w += __shfl_xor(v.w, mask, 64);
    }
    return v;
}

// Kernel A: xp[b,e] = sum_k x[b,k] * W[e,k] + bias[e]
__global__ __launch_bounds__(256) void proj_kernel(
    const float* __restrict__ x, const float* __restrict__ W,
    const float* __restrict__ bias, float* __restrict__ xp,
    float* __restrict__ out)
{
    const int b      = blockIdx.x;
    const int echunk = blockIdx.y;     // 0..3
    const int tid    = threadIdx.x;
    const int lane   = tid & 63;
    const int wave   = tid >> 6;

    const float4* x4 = (const float4*)(x + (size_t)b * E_DIM);
    const float4 xq0 = x4[lane];
    const float4 xq1 = x4[64 + lane];

    const int ebase = echunk * 128;
    for (int e = ebase + wave; e < ebase + 128; e += 4) {
        const float4* w4 = (const float4*)(W + (size_t)e * E_DIM);
        const float4 w0 = w4[lane];
        const float4 w1 = w4[64 + lane];
        float p = w0.x*xq0.x + w0.y*xq0.y + w0.z*xq0.z + w0.w*xq0.w;
        p      += w1.x*xq1.x + w1.y*xq1.y + w1.z*xq1.z + w1.w*xq1.w;
        p = wave_reduce_sum(p);
        if (lane == 0) {
            float v = p + bias[e];
            xp[(size_t)b * E_DIM + e] = v;
            out[(size_t)b * (2 * E_DIM) + e] = v;
        }
    }
}

// Kernel B: flash-decode partials, 4 t-rows per iteration.
// grid (B, NSPLIT), 256 threads (4 waves). Lane owns e = {4*lane..+3, 256+4*lane..+3}.
__global__ __launch_bounds__(256) void attn_partial_kernel(
    const float* __restrict__ enc, const float* __restrict__ xp,
    float* __restrict__ m_part, float* __restrict__ l_part,
    float* __restrict__ acc_part)
{
    const int b    = blockIdx.x;
    const int s    = blockIdx.y;
    const int tid  = threadIdx.x;
    const int lane = tid & 63;
    const int wave = tid >> 6;

    const float4* xp4 = (const float4*)(xp + (size_t)b * E_DIM);
    const float4 xq0 = xp4[lane];
    const float4 xq1 = xp4[64 + lane];

    float m = -INFINITY;
    float l = 0.0f;
    float4 a0 = make_float4(0.f, 0.f, 0.f, 0.f);
    float4 a1 = make_float4(0.f, 0.f, 0.f, 0.f);

    const int t0 = s * TC + wave * TW;
    const size_t row_stride = (size_t)B_DIM * E_DIM;   // floats between t's
    const float* base = enc + ((size_t)t0 * B_DIM + b) * E_DIM;

    #pragma unroll 1
    for (int i = 0; i < TW; i += ROWS) {
        // Issue all 8 row-part loads up front (8 outstanding 16B loads/lane).
        float4 e0[ROWS], e1[ROWS];
        #pragma unroll
        for (int r = 0; r < ROWS; ++r) {
            const float4* e4 = (const float4*)(base + (size_t)(i + r) * row_stride);
            e0[r] = e4[lane];
            e1[r] = e4[64 + lane];
        }

        float4 d;
        {
            float t[ROWS];
            #pragma unroll
            for (int r = 0; r < ROWS; ++r) {
                t[r]  = e0[r].x*xq0.x + e0[r].y*xq0.y + e0[r].z*xq0.z + e0[r].w*xq0.w;
                t[r] += e1[r].x*xq1.x + e1[r].y*xq1.y + e1[r].z*xq1.z + e1[r].w*xq1.w;
            }
            d = make_float4(t[0], t[1], t[2], t[3]);
        }
        d = wave_reduce_sum4(d);     // scores for the 4 rows, same on all lanes

        const float mrow  = fmaxf(fmaxf(d.x, d.y), fmaxf(d.z, d.w));
        const float m_new = fmaxf(m, mrow);
        const float scale = __expf(m - m_new);      // exp(-inf)=0 first time
        const float p0 = __expf(d.x - m_new);
        const float p1 = __expf(d.y - m_new);
        const float p2 = __expf(d.z - m_new);
        const float p3 = __expf(d.w - m_new);
        l = l * scale + (p0 + p1 + p2 + p3);

        a0.x = a0.x*scale + p0*e0[0].x + p1*e0[1].x + p2*e0[2].x + p3*e0[3].x;
        a0.y = a0.y*scale + p0*e0[0].y + p1*e0[1].y + p2*e0[2].y + p3*e0[3].y;
        a0.z = a0.z*scale + p0*e0[0].z + p1*e0[1].z + p2*e0[2].z + p3*e0[3].z;
        a0.w = a0.w*scale + p0*e0[0].w + p1*e0[1].w + p2*e0[2].w + p3*e0[3].w;
        a1.x = a1.x*scale + p0*e1[0].x + p1*e1[1].x + p2*e1[2].x + p3*e1[3].x;
        a1.y = a1.y*scale + p0*e1[0].y + p1*e1[1].y + p2*e1[2].y + p3*e1[3].y;
        a1.z = a1.z*scale + p0*e1[0].z + p1*e1[1].z + p2*e1[2].z + p3*e1[3].z;
        a1.w = a1.w*scale + p0*e1[0].w + p1*e1[1].w + p2*e1[2].w + p3*e1[3].w;
        m = m_new;
    }

    // Combine the 4 waves of this workgroup via LDS.
    __shared__ float lds_m[4];
    __shared__ float lds_l[4];
    __shared__ __align__(16) float lds_acc[4][E_DIM];

    if (lane == 0) lds_m[wave] = m;
    __syncthreads();
    const float M = fmaxf(fmaxf(lds_m[0], lds_m[1]), fmaxf(lds_m[2], lds_m[3]));
    const float wscale = __expf(m - M);   // wave-uniform

    float4* lacc = (float4*)&lds_acc[wave][0];
    lacc[lane]      = make_float4(a0.x*wscale, a0.y*wscale, a0.z*wscale, a0.w*wscale);
    lacc[64 + lane] = make_float4(a1.x*wscale, a1.y*wscale, a1.z*wscale, a1.w*wscale);
    if (lane == 0) lds_l[wave] = l * wscale;
    __syncthreads();

    const int pid = b * NSPLIT + s;
    if (tid == 0) {
        m_part[pid] = M;
        l_part[pid] = lds_l[0] + lds_l[1] + lds_l[2] + lds_l[3];
    }
    if (tid < 128) {   // 128 float4 chunks of the 512-float accumulator
        float4 sum = make_float4(0.f, 0.f, 0.f, 0.f);
        for (int w = 0; w < 4; ++w) {
            const float4 v = ((const float4*)&lds_acc[w][0])[tid];
            sum.x += v.x; sum.y += v.y; sum.z += v.z; sum.w += v.w;
        }
        ((float4*)(acc_part + (size_t)pid * E_DIM))[tid] = sum;
    }
}

// Kernel C: merge NSPLIT partials per b, write context to out[:, 512:1024].
__global__ __launch_bounds__(128) void combine_kernel(
    const float* __restrict__ m_part, const float* __restrict__ l_part,
    const float* __restrict__ acc_part, float* __restrict__ out)
{
    const int b   = blockIdx.x;
    const int tid = threadIdx.x;   // 0..127, one float4 chunk each

    float M = -INFINITY;
    for (int s = 0; s < NSPLIT; ++s) M = fmaxf(M, m_part[b * NSPLIT + s]);
    float w[NSPLIT];
    float L = 0.f;
    for (int s = 0; s < NSPLIT; ++s) {
        w[s] = __expf(m_part[b * NSPLIT + s] - M);
        L += w[s] * l_part[b * NSPLIT + s];
    }
    const float inv = 1.0f / L;

    float4 sum = make_float4(0.f, 0.f, 0.f, 0.f);
    for (int s = 0; s < NSPLIT; ++s) {
        const float4 v = ((const float4*)(acc_part + (size_t)(b * NSPLIT + s) * E_DIM))[tid];
        sum.x += w[s] * v.x; sum.y += w[s] * v.y;
        sum.z += w[s] * v.z; sum.w += w[s] * v.w;
    }
    const float4 r = make_float4(sum.x*inv, sum.y*inv, sum.z*inv, sum.w*inv);
    ((float4*)(out + (size_t)b * (2 * E_DIM) + E_DIM))[tid] = r;
}

extern "C" void kernel_launch(void* const* d_in, const int* in_sizes, int n_in,
                              void* d_out, int out_size, void* d_ws, size_t ws_size,
                              hipStream_t stream) {
    (void)in_sizes; (void)n_in; (void)out_size; (void)ws_size;
    const float* x    = (const float*)d_in[0];   // [B, 512]
    const float* enc  = (const float*)d_in[1];   // [T, B, 512]
    const float* W    = (const float*)d_in[2];   // [512, 512]
    const float* bias = (const float*)d_in[3];   // [512]
    float* out = (float*)d_out;                  // [B, 1024]

    // Workspace (floats): xp[65536] | m_part[2048] | l_part[2048] | acc_part[NSPLIT*B*E]
    float* ws       = (float*)d_ws;
    float* xp       = ws;
    float* m_part   = ws + 65536;
    float* l_part   = ws + 65536 + 2048;
    float* acc_part = ws + 65536 + 4096;

    proj_kernel<<<dim3(B_DIM, 4), 256, 0, stream>>>(x, W, bias, xp, out);
    attn_partial_kernel<<<dim3(B_DIM, NSPLIT), 256, 0, stream>>>(enc, xp, m_part, l_part, acc_part);
    combine_kernel<<<B_DIM, 128, 0, stream>>>(m_part, l_part, acc_part, out);
}

// Round 4
// 695.833 us; speedup vs baseline: 1.0285x; 1.0260x over previous
//
#include <hip/hip_runtime.h>
#include <math.h>

#define T_DIM   2048
#define B_DIM   128
#define E_DIM   512
#define NSPLIT  16
#define TC      (T_DIM / NSPLIT)    // 128 timesteps per workgroup
#define TW      (TC / 4)            // 32 timesteps per wave
#define ROWS    4                   // t-rows batched per iteration

typedef float floatx4 __attribute__((ext_vector_type(4)));

__device__ __forceinline__ float wave_reduce_sum(float v) {
    v += __shfl_xor(v, 1,  64);
    v += __shfl_xor(v, 2,  64);
    v += __shfl_xor(v, 4,  64);
    v += __shfl_xor(v, 8,  64);
    v += __shfl_xor(v, 16, 64);
    v += __shfl_xor(v, 32, 64);
    return v;
}

__device__ __forceinline__ float4 wave_reduce_sum4(float4 v) {
    #pragma unroll
    for (int mask = 1; mask < 64; mask <<= 1) {
        v.x += __shfl_xor(v.x, mask, 64);
        v.y += __shfl_xor(v.y, mask, 64);
        v.z += __shfl_xor(v.z, mask, 64);
        v.w += __shfl_xor(v.w, mask, 64);
    }
    return v;
}

// Non-temporal 16B load via native ext-vector type (builtin rejects HIP_vector_type)
__device__ __forceinline__ floatx4 nt_load4(const float* p) {
    return __builtin_nontemporal_load((const floatx4*)p);
}

// Kernel A: xp[b,e] = sum_k x[b,k] * W[e,k] + bias[e]
__global__ __launch_bounds__(256) void proj_kernel(
    const float* __restrict__ x, const float* __restrict__ W,
    const float* __restrict__ bias, float* __restrict__ xp,
    float* __restrict__ out)
{
    const int b      = blockIdx.x;
    const int echunk = blockIdx.y;     // 0..3
    const int tid    = threadIdx.x;
    const int lane   = tid & 63;
    const int wave   = tid >> 6;

    const float4* x4 = (const float4*)(x + (size_t)b * E_DIM);
    const float4 xq0 = x4[lane];
    const float4 xq1 = x4[64 + lane];

    const int ebase = echunk * 128;
    for (int e = ebase + wave; e < ebase + 128; e += 4) {
        const float4* w4 = (const float4*)(W + (size_t)e * E_DIM);
        const float4 w0 = w4[lane];
        const float4 w1 = w4[64 + lane];
        float p = w0.x*xq0.x + w0.y*xq0.y + w0.z*xq0.z + w0.w*xq0.w;
        p      += w1.x*xq1.x + w1.y*xq1.y + w1.z*xq1.z + w1.w*xq1.w;
        p = wave_reduce_sum(p);
        if (lane == 0) {
            float v = p + bias[e];
            xp[(size_t)b * E_DIM + e] = v;
            out[(size_t)b * (2 * E_DIM) + e] = v;
        }
    }
}

// Kernel B: flash-decode partials, 4 t-rows per iteration, nt enc loads.
// grid (B, NSPLIT), 256 threads (4 waves).
__global__ __launch_bounds__(256) void attn_partial_kernel(
    const float* __restrict__ enc, const float* __restrict__ xp,
    float* __restrict__ m_part, float* __restrict__ l_part,
    float* __restrict__ acc_part)
{
    const int b    = blockIdx.x;
    const int s    = blockIdx.y;
    const int tid  = threadIdx.x;
    const int lane = tid & 63;
    const int wave = tid >> 6;

    const float4* xp4 = (const float4*)(xp + (size_t)b * E_DIM);
    const float4 xq0 = xp4[lane];
    const float4 xq1 = xp4[64 + lane];

    float m = -INFINITY;
    float l = 0.0f;
    float4 a0 = make_float4(0.f, 0.f, 0.f, 0.f);
    float4 a1 = make_float4(0.f, 0.f, 0.f, 0.f);

    const int t0 = s * TC + wave * TW;
    const size_t row_stride = (size_t)B_DIM * E_DIM;   // floats between t's
    const float* base = enc + ((size_t)t0 * B_DIM + b) * E_DIM;

    #pragma unroll 1
    for (int i = 0; i < TW; i += ROWS) {
        floatx4 e0[ROWS], e1[ROWS];
        #pragma unroll
        for (int r = 0; r < ROWS; ++r) {
            const float* erow = base + (size_t)(i + r) * row_stride;
            e0[r] = nt_load4(erow + 4 * lane);
            e1[r] = nt_load4(erow + 4 * (64 + lane));
        }

        float4 d;
        {
            float t[ROWS];
            #pragma unroll
            for (int r = 0; r < ROWS; ++r) {
                t[r]  = e0[r].x*xq0.x + e0[r].y*xq0.y + e0[r].z*xq0.z + e0[r].w*xq0.w;
                t[r] += e1[r].x*xq1.x + e1[r].y*xq1.y + e1[r].z*xq1.z + e1[r].w*xq1.w;
            }
            d = make_float4(t[0], t[1], t[2], t[3]);
        }
        d = wave_reduce_sum4(d);

        const float mrow  = fmaxf(fmaxf(d.x, d.y), fmaxf(d.z, d.w));
        const float m_new = fmaxf(m, mrow);
        const float scale = __expf(m - m_new);
        const float p0 = __expf(d.x - m_new);
        const float p1 = __expf(d.y - m_new);
        const float p2 = __expf(d.z - m_new);
        const float p3 = __expf(d.w - m_new);
        l = l * scale + (p0 + p1 + p2 + p3);

        a0.x = a0.x*scale + p0*e0[0].x + p1*e0[1].x + p2*e0[2].x + p3*e0[3].x;
        a0.y = a0.y*scale + p0*e0[0].y + p1*e0[1].y + p2*e0[2].y + p3*e0[3].y;
        a0.z = a0.z*scale + p0*e0[0].z + p1*e0[1].z + p2*e0[2].z + p3*e0[3].z;
        a0.w = a0.w*scale + p0*e0[0].w + p1*e0[1].w + p2*e0[2].w + p3*e0[3].w;
        a1.x = a1.x*scale + p0*e1[0].x + p1*e1[1].x + p2*e1[2].x + p3*e1[3].x;
        a1.y = a1.y*scale + p0*e1[0].y + p1*e1[1].y + p2*e1[2].y + p3*e1[3].y;
        a1.z = a1.z*scale + p0*e1[0].z + p1*e1[1].z + p2*e1[2].z + p3*e1[3].z;
        a1.w = a1.w*scale + p0*e1[0].w + p1*e1[1].w + p2*e1[2].w + p3*e1[3].w;
        m = m_new;
    }

    __shared__ float lds_m[4];
    __shared__ float lds_l[4];
    __shared__ __align__(16) float lds_acc[4][E_DIM];

    if (lane == 0) lds_m[wave] = m;
    __syncthreads();
    const float M = fmaxf(fmaxf(lds_m[0], lds_m[1]), fmaxf(lds_m[2], lds_m[3]));
    const float wscale = __expf(m - M);

    float4* lacc = (float4*)&lds_acc[wave][0];
    lacc[lane]      = make_float4(a0.x*wscale, a0.y*wscale, a0.z*wscale, a0.w*wscale);
    lacc[64 + lane] = make_float4(a1.x*wscale, a1.y*wscale, a1.z*wscale, a1.w*wscale);
    if (lane == 0) lds_l[wave] = l * wscale;
    __syncthreads();

    const int pid = b * NSPLIT + s;
    if (tid == 0) {
        m_part[pid] = M;
        l_part[pid] = lds_l[0] + lds_l[1] + lds_l[2] + lds_l[3];
    }
    if (tid < 128) {
        float4 sum = make_float4(0.f, 0.f, 0.f, 0.f);
        for (int w = 0; w < 4; ++w) {
            const float4 v = ((const float4*)&lds_acc[w][0])[tid];
            sum.x += v.x; sum.y += v.y; sum.z += v.z; sum.w += v.w;
        }
        ((float4*)(acc_part + (size_t)pid * E_DIM))[tid] = sum;
    }
}

// Kernel C: merge NSPLIT partials per b, write context to out[:, 512:1024].
__global__ __launch_bounds__(128) void combine_kernel(
    const float* __restrict__ m_part, const float* __restrict__ l_part,
    const float* __restrict__ acc_part, float* __restrict__ out)
{
    const int b   = blockIdx.x;
    const int tid = threadIdx.x;

    float M = -INFINITY;
    for (int s = 0; s < NSPLIT; ++s) M = fmaxf(M, m_part[b * NSPLIT + s]);
    float w[NSPLIT];
    float L = 0.f;
    for (int s = 0; s < NSPLIT; ++s) {
        w[s] = __expf(m_part[b * NSPLIT + s] - M);
        L += w[s] * l_part[b * NSPLIT + s];
    }
    const float inv = 1.0f / L;

    float4 sum = make_float4(0.f, 0.f, 0.f, 0.f);
    for (int s = 0; s < NSPLIT; ++s) {
        const float4 v = ((const float4*)(acc_part + (size_t)(b * NSPLIT + s) * E_DIM))[tid];
        sum.x += w[s] * v.x; sum.y += w[s] * v.y;
        sum.z += w[s] * v.z; sum.w += w[s] * v.w;
    }
    const float4 r = make_float4(sum.x*inv, sum.y*inv, sum.z*inv, sum.w*inv);
    ((float4*)(out + (size_t)b * (2 * E_DIM) + E_DIM))[tid] = r;
}

extern "C" void kernel_launch(void* const* d_in, const int* in_sizes, int n_in,
                              void* d_out, int out_size, void* d_ws, size_t ws_size,
                              hipStream_t stream) {
    (void)in_sizes; (void)n_in; (void)out_size; (void)ws_size;
    const float* x    = (const float*)d_in[0];   // [B, 512]
    const float* enc  = (const float*)d_in[1];   // [T, B, 512]
    const float* W    = (const float*)d_in[2];   // [512, 512]
    const float* bias = (const float*)d_in[3];   // [512]
    float* out = (float*)d_out;                  // [B, 1024]

    float* ws       = (float*)d_ws;
    float* xp       = ws;
    float* m_part   = ws + 65536;
    float* l_part   = ws + 65536 + 2048;
    float* acc_part = ws + 65536 + 4096;

    proj_kernel<<<dim3(B_DIM, 4), 256, 0, stream>>>(x, W, bias, xp, out);
    attn_partial_kernel<<<dim3(B_DIM, NSPLIT), 256, 0, stream>>>(enc, xp, m_part, l_part, acc_part);
    combine_kernel<<<B_DIM, 128, 0, stream>>>(m_part, l_part, acc_part, out);
}